// Round 1
// 70.823 us; speedup vs baseline: 1.1647x; 1.1647x over previous
//
#include <hip/hip_runtime.h>

// Problem constants (from reference setup_inputs)
#define NN 8
#define CC 4
#define HH 64
#define WW 64
#define KK 5
#define FF 16
#define HO 60
#define WO 60
#define PP (KK * KK * CC) /* 100 */

typedef float v4f __attribute__((ext_vector_type(4)));
typedef float v2f __attribute__((ext_vector_type(2)));

// Single fused kernel. Theory: previous version mixed s_load (SMEM) and
// ds_read (LDS) in the inner loop -> both count in lgkmcnt, SMEM returns
// out-of-order -> compiler emits lgkmcnt(0) full drains every iteration,
// exposing ~200-400cy latency at ~1.9 waves/SIMD occupancy.
// Fix: weights ALSO staged in LDS (homogeneous in-order DS traffic,
// partial lgkmcnt waits), 8 waves/block via c-split (2x occupancy),
// weight quads laid out as f-pairs {A_a,A_b,B_a,B_b} so the inner math is
// <2 x float> fma -> v_pk_fma_f32 on gfx950 (falls back to 2x v_fma, no risk).
//
// Block = one (n, ho): 512 threads = 8 waves.
//   wave wid: fg = wid&3 (feature group of 4: f = 4*fg..4*fg+3)
//             ch = wid>>2 (c-half: c in {2ch, 2ch+1})
//   lane = w position (60 used of 64).
// LDS:
//   pq   : pixel quads (E1, x*E1, E2, -x*E2) for rows ho..ho+4, all c, w 0..63
//   wlds : weight quads [p][side][f2] = {e^ka, e^kb, ka*e^ka, kb*e^kb},
//          f2 = f-pair index (features 2*f2, 2*f2+1); 100*2*8 = 1600 quads
//   red  : c-half reduction buffer [fg][8 v2f accs][64 lanes]
__global__ __launch_bounds__(512) void smorph_fused(
        const float* __restrict__ x, const float* __restrict__ k1,
        const float* __restrict__ k2, const float* __restrict__ bias,
        float* __restrict__ out) {
    __shared__ v4f pq[CC * KK * 64 + 4];   // +4 pad: lanes 60-63 read wo+kw<=67
    __shared__ v4f wlds[PP * 16];          // 25.6 KB
    __shared__ v2f red[4 * 8 * 64];        // 16 KB

    int b = blockIdx.x; // 0..479 = (n, ho)
    int n = b / HO;
    int ho = b - n * HO;
    int t = threadIdx.x;

    // Stage weight exp-quads (redundant per block, ~3 iters of cheap VALU;
    // k1/k2 reads are L2-resident after the first blocks).
    for (int i = t; i < PP * 16; i += 512) {
        int p = i >> 4, rem = i & 15, side = rem >> 3, f2 = rem & 7;
        const float* kp = side ? k2 : k1;
        float ka = kp[p * FF + 2 * f2];
        float kb = kp[p * FF + 2 * f2 + 1];
        float ea = __expf(ka), eb = __expf(kb);
        v4f wv = {ea, eb, ka * ea, kb * eb};
        wlds[i] = wv;
    }
    // Stage pixel exp-quads: rows ho..ho+4 (ho+4 <= 63 always), all c, w 0..63.
    for (int i = t; i < CC * KK * 64; i += 512) {
        int w = i & 63;
        int cr = i >> 6; // c*KK + r
        int c = cr / KK, r = cr - c * KK;
        float v = x[((n * CC + c) * HH + (ho + r)) * WW + w];
        float e1 = __expf(v), e2 = __expf(-v);
        v4f qv = {e1, v * e1, e2, -v * e2};
        pq[i] = qv;
    }
    __syncthreads();

    int lane = t & 63;        // w position
    int wid = t >> 6;         // 0..7
    int fg = wid & 3;         // feature group
    int ch = wid >> 2;        // c-half
    int fp2 = fg * 2;         // f-pair base index

    v2f d1[2], n1[2], d2[2], n2[2];
#pragma unroll
    for (int jj = 0; jj < 2; ++jj) {
        d1[jj] = 0.f; n1[jj] = 0.f; d2[jj] = 0.f; n2[jj] = 0.f;
    }

#pragma unroll 1
    for (int ci = 0; ci < 2; ++ci) {
        int c = ch * 2 + ci;
#pragma unroll
        for (int kh = 0; kh < KK; ++kh) {
            const v4f* prow = &pq[(c * KK + kh) * 64 + lane];
#pragma unroll
            for (int kw = 0; kw < KK; ++kw) {
                v4f q = prow[kw]; // ds_read_b128, consecutive lanes
                // p = (kh*KK + kw)*CC + c  (reference patch order: kh,kw,c)
                const v4f* wp = &wlds[((kh * KK + kw) * CC + c) * 16 + fp2];
#pragma unroll
                for (int jp = 0; jp < 2; ++jp) {
                    v4f w1 = wp[jp];     // side-1 quad {A1a,A1b,B1a,B1b}
                    v4f w2 = wp[8 + jp]; // side-2 quad {A2a,A2b,B2a,B2b}
                    // 3 v2f fmas per side per f-pair (v_pk_fma_f32 candidates)
                    d1[jp] += q.xx * w1.xy;
                    n1[jp] += q.yy * w1.xy + q.xx * w1.zw;
                    d2[jp] += q.zz * w2.xy;
                    n2[jp] += q.ww * w2.xy + q.zz * w2.zw;
                }
            }
        }
    }

    // c-half reduction: ch==1 waves dump partials, ch==0 waves combine.
    v2f* rr = &red[fg * 8 * 64 + lane];
    if (ch) {
        rr[0 * 64] = d1[0]; rr[1 * 64] = d1[1];
        rr[2 * 64] = n1[0]; rr[3 * 64] = n1[1];
        rr[4 * 64] = d2[0]; rr[5 * 64] = d2[1];
        rr[6 * 64] = n2[0]; rr[7 * 64] = n2[1];
    }
    __syncthreads();
    if (!ch && lane < WO) {
        d1[0] += rr[0 * 64]; d1[1] += rr[1 * 64];
        n1[0] += rr[2 * 64]; n1[1] += rr[3 * 64];
        d2[0] += rr[4 * 64]; d2[1] += rr[5 * 64];
        n2[0] += rr[6 * 64]; n2[1] += rr[7 * 64];
#pragma unroll
        for (int jp = 0; jp < 2; ++jp) {
            v2f o = n1[jp] / d1[jp] + n2[jp] / d2[jp];
            int f0 = fg * 4 + 2 * jp;
            out[((size_t)(n * FF + f0) * HO + ho) * WO + lane] = o.x + bias[f0];
            out[((size_t)(n * FF + f0 + 1) * HO + ho) * WO + lane] =
                o.y + bias[f0 + 1];
        }
    }
}

extern "C" void kernel_launch(void* const* d_in, const int* in_sizes, int n_in,
                              void* d_out, int out_size, void* d_ws, size_t ws_size,
                              hipStream_t stream) {
    const float* x    = (const float*)d_in[0];
    const float* k1   = (const float*)d_in[1];
    const float* k2   = (const float*)d_in[2];
    const float* bias = (const float*)d_in[3];
    float* out = (float*)d_out;

    // 8 n * 60 ho = 480 blocks, 512 threads (8 waves: 4 f-groups x 2 c-halves)
    smorph_fused<<<480, 512, 0, stream>>>(x, k1, k2, bias, out);
}